// Round 2
// baseline (537.837 us; speedup 1.0000x reference)
//
#include <hip/hip_runtime.h>

// RelativePositionEncoding: out[1,1024,1024,128] f32.
// out[i,j,:] = W_si[d_si] + W_ti[d_ti] + bent*w_ent + W_sym[d_sym]
// with W_si=W[0:66], W_ti=W[66:132], w_ent=W[132], W_sym=W[133:139].
// Pure HBM-write-bound (~537 MB out); W staged in LDS, bins precomputed per block.

#define SEQ_L 1024
#define NROWS 139
#define NW4   32              // float4 per 128-dim row
#define W4_TOTAL (NROWS * NW4) // 4448 float4 = 71,168 B

typedef float vf4 __attribute__((ext_vector_type(4)));

__global__ __launch_bounds__(256, 2)
void rpe_kernel(const int* __restrict__ seq_index,
                const int* __restrict__ seq_color,
                const int* __restrict__ seq_sym,
                const int* __restrict__ seq_entity,
                const int* __restrict__ token_index,
                const float* __restrict__ W,
                float* __restrict__ out)
{
    __shared__ vf4 w_lds[W4_TOTAL];      // 71,168 B
    __shared__ int bins[SEQ_L];          //  4,096 B

    const int t = threadIdx.x;
    const int i = blockIdx.x;

    // Per-row (i) values — wave-uniform, compiler emits scalar loads.
    const int si_i  = seq_index[i];
    const int col_i = seq_color[i];
    const int sym_i = seq_sym[i];
    const int ent_i = seq_entity[i];
    const int ti_i  = token_index[i];

    // Stage W into LDS (coalesced 16B loads; L2-hot after first blocks).
    const vf4* W4 = (const vf4*)W;
    for (int idx = t; idx < W4_TOTAL; idx += 256) {
        w_lds[idx] = W4[idx];
    }

    // Precompute packed bins for every j (once per block).
    for (int j = t; j < SEQ_L; j += 256) {
        const int cj  = seq_color[j];
        const int sj  = seq_index[j];
        const int ej  = seq_entity[j];
        int dsi = 65, dti = 65, dsym = 5, bent = 0;
        if (cj == col_i) {
            int d = si_i - sj;
            d = min(max(d, -32), 32) + 32;
            dsi = d;
            if (sj == si_i) {
                int dt = ti_i - token_index[j];
                dt = min(max(dt, -32), 32) + 32;
                dti = dt;
            }
        }
        if (ej == ent_i) {
            bent = 1;
            int ds = sym_i - seq_sym[j];
            ds = min(max(ds, -2), 2) + 2;
            dsym = ds;
        }
        bins[j] = dsi | (dti << 8) | (dsym << 16) | (bent << 24);
    }
    __syncthreads();

    const int g  = t & 31;   // which float4 of the 32 covering 128 dims
    const int j0 = t >> 5;   // 8 j's per block-iteration

    // Entity row lives in registers for the whole loop.
    const vf4 went = w_lds[132 * NW4 + g];

    vf4* out4 = (vf4*)out + (size_t)i * (SEQ_L * NW4);

    #pragma unroll 4
    for (int j = j0; j < SEQ_L; j += 8) {
        const int pack = bins[j];
        const int dsi  =  pack        & 0xff;
        const int dti  = (pack >> 8)  & 0xff;
        const int dsym = (pack >> 16) & 0xff;
        const float be = (float)(pack >> 24);  // 0 or 1

        const vf4 a = w_lds[dsi * NW4 + g];
        const vf4 b = w_lds[(66 + dti) * NW4 + g];
        const vf4 c = w_lds[(133 + dsym) * NW4 + g];

        vf4 r = a + b + c + be * went;

        __builtin_nontemporal_store(r, &out4[j * NW4 + g]);
    }
}

extern "C" void kernel_launch(void* const* d_in, const int* in_sizes, int n_in,
                              void* d_out, int out_size, void* d_ws, size_t ws_size,
                              hipStream_t stream) {
    const int*   seq_index   = (const int*)d_in[0];
    const int*   seq_color   = (const int*)d_in[1];
    const int*   seq_sym     = (const int*)d_in[2];
    const int*   seq_entity  = (const int*)d_in[3];
    const int*   token_index = (const int*)d_in[4];
    const float* W           = (const float*)d_in[5];
    float*       out         = (float*)d_out;

    rpe_kernel<<<SEQ_L, 256, 0, stream>>>(seq_index, seq_color, seq_sym,
                                          seq_entity, token_index, W, out);
}

// Round 3
// 535.596 us; speedup vs baseline: 1.0042x; 1.0042x over previous
//
#include <hip/hip_runtime.h>

// RelativePositionEncoding: out[1,1024,1024,128] f32 (537 MB, write-bound).
// out[i,j,:] = W_si[d_si] + W_ti[d_ti] + bent*w_ent + W_sym[d_sym]
// R2: drop the 71KB LDS W-tile (W is L1/L2-hot; 3x read amplification is
// absorbed by cache), keep only 4KB bins in LDS -> one dependent hop,
// 4 blocks/CU instead of 2.

#define SEQ_L 1024
#define NW4   32   // float4 per 128-dim row

typedef float vf4 __attribute__((ext_vector_type(4)));

__global__ __launch_bounds__(256, 4)
void rpe_kernel(const int* __restrict__ seq_index,
                const int* __restrict__ seq_color,
                const int* __restrict__ seq_sym,
                const int* __restrict__ seq_entity,
                const int* __restrict__ token_index,
                const float* __restrict__ W,
                float* __restrict__ out)
{
    __shared__ int bins[SEQ_L];   // 4 KB only

    const int t = threadIdx.x;
    const int i = blockIdx.x;

    // Per-row (i) values — wave-uniform -> scalar loads.
    const int si_i  = seq_index[i];
    const int col_i = seq_color[i];
    const int sym_i = seq_sym[i];
    const int ent_i = seq_entity[i];
    const int ti_i  = token_index[i];

    // Precompute packed bins for every j (once per block).
    for (int j = t; j < SEQ_L; j += 256) {
        const int cj = seq_color[j];
        const int sj = seq_index[j];
        const int ej = seq_entity[j];
        int dsi = 65, dti = 65, dsym = 5, bent = 0;
        if (cj == col_i) {
            int d = si_i - sj;
            d = min(max(d, -32), 32) + 32;
            dsi = d;
            if (sj == si_i) {
                int dt = ti_i - token_index[j];
                dt = min(max(dt, -32), 32) + 32;
                dti = dt;
            }
        }
        if (ej == ent_i) {
            bent = 1;
            int ds = sym_i - seq_sym[j];
            ds = min(max(ds, -2), 2) + 2;
            dsym = ds;
        }
        bins[j] = dsi | (dti << 8) | (dsym << 16) | (bent << 24);
    }
    __syncthreads();

    const int g  = t & 31;   // which float4 of the 32 covering 128 dims
    const int j0 = t >> 5;   // 8 j's per block-iteration

    const vf4* W4 = (const vf4*)W;

    // Entity row slice in registers for the whole loop (L2-hot load).
    const vf4 went = W4[132 * NW4 + g];

    vf4* out4 = (vf4*)out + (size_t)i * (SEQ_L * NW4);

    #pragma unroll 4
    for (int j = j0; j < SEQ_L; j += 8) {
        const int pack = bins[j];
        const int dsi  =  pack        & 0xff;
        const int dti  = (pack >> 8)  & 0xff;
        const int dsym = (pack >> 16) & 0xff;
        const float be = (float)(pack >> 24);  // 0 or 1

        // Coalesced 512B-per-half-wave loads, L1/L2 resident (W = 71 KB).
        const vf4 a = W4[dsi * NW4 + g];
        const vf4 b = W4[(66 + dti) * NW4 + g];
        const vf4 c = W4[(133 + dsym) * NW4 + g];

        vf4 r = a + b + c + be * went;

        __builtin_nontemporal_store(r, &out4[j * NW4 + g]);
    }
}

extern "C" void kernel_launch(void* const* d_in, const int* in_sizes, int n_in,
                              void* d_out, int out_size, void* d_ws, size_t ws_size,
                              hipStream_t stream) {
    const int*   seq_index   = (const int*)d_in[0];
    const int*   seq_color   = (const int*)d_in[1];
    const int*   seq_sym     = (const int*)d_in[2];
    const int*   seq_entity  = (const int*)d_in[3];
    const int*   token_index = (const int*)d_in[4];
    const float* W           = (const float*)d_in[5];
    float*       out         = (float*)d_out;

    rpe_kernel<<<SEQ_L, 256, 0, stream>>>(seq_index, seq_color, seq_sym,
                                          seq_entity, token_index, W, out);
}